// Round 4
// baseline (350.452 us; speedup 1.0000x reference)
//
#include <hip/hip_runtime.h>
#include <cstdint>
#include <cstddef>

// ---------------------------------------------------------------------------
// MultiheadAttention (double-softmax), MI355X. B=4,S=1024,D=1024,H=16.
// Inputs FP32 (dict order), output FP32. r15:247.0 r16:240.1 r17:338.9(!).
// r18: r17's qkv spilled (arch-VGPR demand 112 + 64 AGPR acc > ~170 cap at
// 3 waves/EU -> WRITE_SIZE 180MB scratch, 160 µs). Fix: prefetch depth 2->1
// (X only, -32 arch regs => ~144 total, fits). Same counted-vmcnt schedule:
// per 32-K phase: gll(t+1) x2 -> cvt_pk X->af -> reload X -> 16 MFMA ->
// s_waitcnt vmcnt(8) (retires only the glls, FIFO) -> s_barrier.
// attn keeps r17 swapped-QK^T + in-register P redistribution (neutral time,
// -7.3M bank conflicts, passed).
//   K0 cvt4: Wo,Wq,Wk,Wv fp32->bf16 into d_out[0,8MB) (dead until ln)
//   K1 qkv : q,k -> [B,S,D] bf16 (q*0.125*log2e); v -> [B,H,dk,S] bf16
//   K2 attn: two-pass double softmax, no-max softmax1 (scores << 88)
//   K3 outp: 64x128 tiles, ctx @ Wo_bf^T + bo -> pre bf16
//   K4 ln  : LayerNorm(pre + Q)*g + b -> d_out f32 [0,16MB)
// ws (24 MB): qb[0,8) kb[8,16) vb[16,24); pre bf16 aliases [0,8) (qb dead).
// d_out u16 view: wo[0,1M) wq[1M,2M) wk[2M,3M) wv[3M,4M) ctx[4M,8M).
// ---------------------------------------------------------------------------

typedef unsigned short ushort_t;
typedef __attribute__((ext_vector_type(8))) short bf16x8;     // MFMA A/B frag
typedef __attribute__((ext_vector_type(8))) unsigned short us8;
typedef __attribute__((ext_vector_type(4))) unsigned short us4;
typedef __attribute__((ext_vector_type(4))) float f32x4;      // MFMA C/D frag

#define MFMA16(a, b, c) __builtin_amdgcn_mfma_f32_16x16x32_bf16((a), (b), (c), 0, 0, 0)
#define EXP2F(x) __builtin_amdgcn_exp2f(x)
#define LOG2E 1.4426950408889634f

__device__ __forceinline__ float b2f(ushort_t u) {
  union { unsigned int i; float f; } x; x.i = ((unsigned int)u) << 16; return x.f;
}
__device__ __forceinline__ ushort_t f2b(float f) {
  union { unsigned int i; float f; } x; x.f = f;
  unsigned int r = (x.i + 0x7FFFu + ((x.i >> 16) & 1u)) >> 16;  // RNE
  return (ushort_t)r;
}
__device__ __forceinline__ us8 cvt8(float4 a, float4 b) {
  us8 r;
  r[0] = f2b(a.x); r[1] = f2b(a.y); r[2] = f2b(a.z); r[3] = f2b(a.w);
  r[4] = f2b(b.x); r[5] = f2b(b.y); r[6] = f2b(b.z); r[7] = f2b(b.w);
  return r;
}
// HW packed f32->bf16 (RNE), 2 values / instruction.
__device__ __forceinline__ unsigned int cvtpk(float lo, float hi) {
  unsigned int r;
  asm("v_cvt_pk_bf16_f32 %0, %1, %2" : "=v"(r) : "v"(lo), "v"(hi));
  return r;
}
__device__ __forceinline__ bf16x8 cvt8pk(float4 a, float4 b) {
  union { unsigned int u[4]; bf16x8 v; } r;
  r.u[0] = cvtpk(a.x, a.y); r.u[1] = cvtpk(a.z, a.w);
  r.u[2] = cvtpk(b.x, b.y); r.u[3] = cvtpk(b.z, b.w);
  return r.v;
}

// async global->LDS, 16B per lane; lds base must be wave-uniform.
__device__ __forceinline__ void gll16(const ushort_t* g, ushort_t* l) {
  __builtin_amdgcn_global_load_lds(
      (const __attribute__((address_space(1))) void*)g,
      (__attribute__((address_space(3))) void*)l, 16, 0, 0);
}

// ---------------------------------------------------------------------------
// K0: convert 4 weight matrices (1M fp32 elems each) to bf16.
// ---------------------------------------------------------------------------
__global__ __launch_bounds__(256, 8) void cvt4_kernel(
    const float* __restrict__ w0, const float* __restrict__ w1,
    const float* __restrict__ w2, const float* __restrict__ w3,
    ushort_t* __restrict__ dst) {
  const int which = blockIdx.y;
  const float* src = (which == 0) ? w0 : (which == 1) ? w1 : (which == 2) ? w2 : w3;
  const int i = (blockIdx.x * 256 + threadIdx.x) * 8;
  const float4 a = *(const float4*)(src + i);
  const float4 b = *(const float4*)(src + i + 4);
  *(us8*)(dst + (size_t)which * 1048576 + i) = cvt8(a, b);
}

// ---------------------------------------------------------------------------
// K1: Q/K/V projections. 128x128 tile, BK=32. A (fp32) global->reg->cvt_pk,
// never staged in LDS (frag rows are lane-indexed); 1-phase prefetch depth.
// B (bf16) via gll into ping-pong LDS. Raw s_barrier + counted vmcnt(8):
// only the 2 gll for the next buffer drain at each barrier; the 8 A-loads
// stay in flight. Grid (256,1,3) = 3 blocks/CU.
// Steady-state vmcnt ledger per phase: top = X(8); +gll(2) -> 10; cvt waits
// vmcnt(2) [X ready, keep glls]; +X'(8) -> 10; end waits vmcnt(8) [retire
// glls, keep X']; barrier. Arch regs ~80 + 64 acc AGPR = ~144 < 170 cap.
// ---------------------------------------------------------------------------
__global__ __launch_bounds__(256, 3) void qkv_proj_kernel(
    const float* __restrict__ Qin, const float* __restrict__ Kin,
    const float* __restrict__ Vin,
    const ushort_t* __restrict__ wq, const ushort_t* __restrict__ wk,
    const ushort_t* __restrict__ wv,
    const float* __restrict__ bq, const float* __restrict__ bk,
    const float* __restrict__ bv,
    ushort_t* __restrict__ qb, ushort_t* __restrict__ kb,
    ushort_t* __restrict__ vb) {
  __shared__ __align__(16) ushort_t Bsl0[128 * 32];
  __shared__ __align__(16) ushort_t Bsl1[128 * 32];
  const float* A; const ushort_t* W; const float* bias; float scale;
  if (blockIdx.z == 0)      { A = Qin; W = wq; bias = bq; scale = 0.125f * LOG2E; }
  else if (blockIdx.z == 1) { A = Kin; W = wk; bias = bk; scale = 1.0f; }
  else                      { A = Vin; W = wv; bias = bv; scale = 1.0f; }
  const int l = blockIdx.x;
  const int xcd = l & 7, ii = l >> 3;
  const int m0 = (xcd * 4 + (ii >> 3)) * 128;
  const int n0 = (ii & 7) * 128;
  const int tid = threadIdx.x;
  const int wave = tid >> 6, lane = tid & 63;
  const int l15 = lane & 15, quad = lane >> 4;
  const int wr = wave >> 1, wc = wave & 1;

  // A fragment rows: lane l15 = row within 16-subtile, quad*8 = k offset.
  const float* Ap[4];
#pragma unroll
  for (int s = 0; s < 4; ++s)
    Ap[s] = A + (size_t)(m0 + wr * 64 + s * 16 + l15) * 1024 + quad * 8;

  // B staging via gll: wave w covers dest rows w*32..+15 and +16..+31.
  const ushort_t* Bg0 = W + (size_t)(n0 + wave * 32 + (lane >> 2)) * 1024 + (lane & 3) * 8;
  const ushort_t* Bg1 = W + (size_t)(n0 + wave * 32 + 16 + (lane >> 2)) * 1024 + (lane & 3) * 8;
  ushort_t* Bl0a = Bsl0 + wave * 1024; ushort_t* Bl0b = Bl0a + 512;
  ushort_t* Bl1a = Bsl1 + wave * 1024; ushort_t* Bl1b = Bl1a + 512;

  // prologue: X <- k=0, gll(0)->Bsl0, drain all, barrier.
  float4 X[4][2];
#pragma unroll
  for (int s = 0; s < 4; ++s) { X[s][0] = *(const float4*)(Ap[s]); X[s][1] = *(const float4*)(Ap[s] + 4); }
  gll16(Bg0, Bl0a);
  gll16(Bg1, Bl0b);
  asm volatile("s_waitcnt vmcnt(0)" ::: "memory");
  __builtin_amdgcn_s_barrier();

  f32x4 acc[4][4] = {};
#define QKV_MFMA(AFR, BSL)                                                      \
  {                                                                             \
    bf16x8 bfr[4];                                                              \
    _Pragma("unroll") for (int s = 0; s < 4; ++s)                               \
        bfr[s] = *(const bf16x8*)((BSL) + (wc * 64 + s * 16 + l15) * 32 + quad * 8); \
    _Pragma("unroll") for (int ms = 0; ms < 4; ++ms)                            \
        _Pragma("unroll") for (int ns = 0; ns < 4; ++ns)                        \
            acc[ms][ns] = MFMA16((AFR)[ms], bfr[ns], acc[ms][ns]);              \
  }

  for (int k0 = 0; k0 < 1024; k0 += 64) {
    // phase A: compute tile k0 (X + Bsl0); gll k0+32 -> Bsl1; X <- k0+32
    gll16(Bg0 + k0 + 32, Bl1a);
    gll16(Bg1 + k0 + 32, Bl1b);
    {
      bf16x8 af[4];
#pragma unroll
      for (int s = 0; s < 4; ++s) {
        af[s] = cvt8pk(X[s][0], X[s][1]);
        X[s][0] = *(const float4*)(Ap[s] + k0 + 32);
        X[s][1] = *(const float4*)(Ap[s] + k0 + 36);
      }
      QKV_MFMA(af, Bsl0)
    }
    asm volatile("s_waitcnt vmcnt(8)" ::: "memory");
    __builtin_amdgcn_s_barrier();
    // phase B: compute tile k0+32 (X + Bsl1); gll k0+64 -> Bsl0; X <- k0+64
    if (k0 + 64 < 1024) {
      gll16(Bg0 + k0 + 64, Bl0a);
      gll16(Bg1 + k0 + 64, Bl0b);
      bf16x8 af[4];
#pragma unroll
      for (int s = 0; s < 4; ++s) {
        af[s] = cvt8pk(X[s][0], X[s][1]);
        X[s][0] = *(const float4*)(Ap[s] + k0 + 64);
        X[s][1] = *(const float4*)(Ap[s] + k0 + 68);
      }
      QKV_MFMA(af, Bsl1)
      asm volatile("s_waitcnt vmcnt(8)" ::: "memory");
      __builtin_amdgcn_s_barrier();
    } else {
      // final tile: no prefetch, no barrier needed after.
      bf16x8 af[4];
#pragma unroll
      for (int s = 0; s < 4; ++s) af[s] = cvt8pk(X[s][0], X[s][1]);
      QKV_MFMA(af, Bsl1)
    }
  }
#undef QKV_MFMA

  if (blockIdx.z != 2) {
    ushort_t* outp = (blockIdx.z == 0) ? qb : kb;
#pragma unroll
    for (int ns = 0; ns < 4; ++ns) {
      const int col = n0 + wc * 64 + ns * 16 + l15;
      const float bv_ = bias[col];
#pragma unroll
      for (int ms = 0; ms < 4; ++ms) {
        const int rowb = m0 + wr * 64 + ms * 16 + quad * 4;
#pragma unroll
        for (int r = 0; r < 4; ++r) {
          outp[(size_t)(rowb + r) * 1024 + col] =
              f2b((acc[ms][ns][r] + bv_) * scale);
        }
      }
    }
  } else {
    // V transposed: vb[((b*16+h)*64 + d)*1024 + s]
#pragma unroll
    for (int ns = 0; ns < 4; ++ns) {
      const int col = n0 + wc * 64 + ns * 16 + l15;
      const float bv_ = bias[col];
      const int h = col >> 6, d = col & 63;
#pragma unroll
      for (int ms = 0; ms < 4; ++ms) {
        const int i0 = m0 + wr * 64 + ms * 16 + quad * 4;
        const int b = i0 >> 10, s0 = i0 & 1023;
        us4 pack;
#pragma unroll
        for (int r = 0; r < 4; ++r) pack[r] = f2b(acc[ms][ns][r] + bv_);
        *(us4*)(vb + ((size_t)(b * 16 + h) * 64 + d) * 1024 + s0) = pack;
      }
    }
  }
}

// ---------------------------------------------------------------------------
// K2: attention, double softmax, SWAPPED QK^T: sc = mfma(K_frag, Q_frag) so
// thread (quad,l15) holds S[k = ns*16+quad*4+r][q = l15]. Softmax sums are
// scalar per thread (reduce over quads: 2 shuffles). P->PV redistribution
// in-register: cvt_pk pairs + 16 ds_bpermute + 8 cndmask (cross-quad move,
// same l15). PV: oac = mfma(V_frag, P_frag) -> O^T[d][q], d contiguous in
// regs -> 4 packed us4 ctx stores. No Ps LDS, no lgkm hard-sync.
// Grid 1024 (swizzled: xcd owns 8 bh x 16 q-tiles).
// ---------------------------------------------------------------------------
__global__ __launch_bounds__(256, 4) void attn_kernel(
    const ushort_t* __restrict__ qb, const ushort_t* __restrict__ kb,
    const ushort_t* __restrict__ vb, ushort_t* __restrict__ ctx) {
  __shared__ __align__(16) ushort_t Qs[64 * 72];
  __shared__ __align__(16) ushort_t Ks[64 * 72];
  __shared__ __align__(16) ushort_t Vt[64 * 72];

  const int tid = threadIdx.x, wave = tid >> 6, lane = tid & 63;
  const int l15 = lane & 15, quad = lane >> 4;
  // XCD-aware swizzle
  const int l = blockIdx.x;
  const int xcd = l & 7, ii = l >> 3;
  const int bh = xcd * 8 + (ii >> 4);
  const int q0 = (ii & 15) * 64;
  const int b = bh >> 4, h = bh & 15;
  const ushort_t* qg = qb + ((size_t)b << 20) + h * 64;
  const ushort_t* kg = kb + ((size_t)b << 20) + h * 64;
  const ushort_t* vg = vb + ((size_t)bh << 16);   // [dk][S]

  const int kr0 = tid >> 3, kc0 = (tid & 7) * 8;
  const int kr1 = (tid + 256) >> 3, kc1 = kc0;

  *(us8*)(Qs + kr0 * 72 + kc0) = *(const us8*)(qg + (size_t)(q0 + kr0) * 1024 + kc0);
  *(us8*)(Qs + kr1 * 72 + kc1) = *(const us8*)(qg + (size_t)(q0 + kr1) * 1024 + kc1);
  __syncthreads();
  // Q fragments (B-operand: lane l15 = q-col, quad*8 = k) — kt-invariant.
  bf16x8 aqh[2];
  aqh[0] = *(const bf16x8*)(Qs + (wave * 16 + l15) * 72 + quad * 8);
  aqh[1] = *(const bf16x8*)(Qs + (wave * 16 + l15) * 72 + 32 + quad * 8);

  // ---- pass 1: Z1 only ----
  float z1 = 0.f;
  us8 rk0 = *(const us8*)(kg + (size_t)kr0 * 1024 + kc0);
  us8 rk1 = *(const us8*)(kg + (size_t)kr1 * 1024 + kc1);
  for (int kt = 0; kt < 16; ++kt) {
    __syncthreads();
    *(us8*)(Ks + kr0 * 72 + kc0) = rk0;
    *(us8*)(Ks + kr1 * 72 + kc1) = rk1;
    __syncthreads();
    if (kt < 15) {
      rk0 = *(const us8*)(kg + (size_t)((kt + 1) * 64 + kr0) * 1024 + kc0);
      rk1 = *(const us8*)(kg + (size_t)((kt + 1) * 64 + kr1) * 1024 + kc1);
    }
    f32x4 sc[4] = {};
#pragma unroll
    for (int kk = 0; kk < 2; ++kk) {
#pragma unroll
      for (int ns = 0; ns < 4; ++ns) {
        const bf16x8 kf = *(const bf16x8*)(Ks + (ns * 16 + l15) * 72 + kk * 32 + quad * 8);
        sc[ns] = MFMA16(kf, aqh[kk], sc[ns]);   // swapped: rows=k, cols=q
      }
    }
#pragma unroll
    for (int ns = 0; ns < 4; ++ns)
#pragma unroll
      for (int r = 0; r < 4; ++r) z1 += EXP2F(sc[ns][r]);
  }
  z1 += __shfl_xor(z1, 16, 64);
  z1 += __shfl_xor(z1, 32, 64);
  const float iz1 = LOG2E / z1;    // e2 = exp2(exp2(sc) * iz1)

  // bpermute source addrs (bytes): src lane = ((quad&1)*2 + (t>>1))*16 + l15
  const int adr0 = ((((quad & 1) << 1) * 16) + l15) << 2;
  const int adr1 = adr0 + 64;

  // ---- pass 2 ----
  f32x4 oac[4] = {};
  float z2 = 0.f;
  rk0 = *(const us8*)(kg + (size_t)kr0 * 1024 + kc0);
  rk1 = *(const us8*)(kg + (size_t)kr1 * 1024 + kc1);
  us8 rv0 = *(const us8*)(vg + (size_t)kr0 * 1024 + kc0);
  us8 rv1 = *(const us8*)(vg + (size_t)kr1 * 1024 + kc1);
  for (int kt = 0; kt < 16; ++kt) {
    __syncthreads();
    *(us8*)(Ks + kr0 * 72 + kc0) = rk0;
    *(us8*)(Ks + kr1 * 72 + kc1) = rk1;
    *(us8*)(Vt + kr0 * 72 + kc0) = rv0;
    *(us8*)(Vt + kr1 * 72 + kc1) = rv1;
    __syncthreads();
    if (kt < 15) {
      rk0 = *(const us8*)(kg + (size_t)((kt + 1) * 64 + kr0) * 1024 + kc0);
      rk1 = *(const us8*)(kg + (size_t)((kt + 1) * 64 + kr1) * 1024 + kc1);
      rv0 = *(const us8*)(vg + (size_t)kr0 * 1024 + (kt + 1) * 64 + kc0);
      rv1 = *(const us8*)(vg + (size_t)kr1 * 1024 + (kt + 1) * 64 + kc1);
    }
    f32x4 sc[4] = {};
#pragma unroll
    for (int kk = 0; kk < 2; ++kk) {
#pragma unroll
      for (int ns = 0; ns < 4; ++ns) {
        const bf16x8 kf = *(const bf16x8*)(Ks + (ns * 16 + l15) * 72 + kk * 32 + quad * 8);
        sc[ns] = MFMA16(kf, aqh[kk], sc[ns]);
      }
    }
    // softmax epilogue: e2 per score; pack k-pairs (per thread: q=l15 fixed,
    // k = ns*16 + quad*4 + r).
    unsigned int D[4][2];
#pragma unroll
    for (int ns = 0; ns < 4; ++ns) {
      const float e0 = EXP2F(EXP2F(sc[ns][0]) * iz1);
      const float e1 = EXP2F(EXP2F(sc[ns][1]) * iz1);
      const float e2 = EXP2F(EXP2F(sc[ns][2]) * iz1);
      const float e3 = EXP2F(EXP2F(sc[ns][3]) * iz1);
      z2 += (e0 + e1) + (e2 + e3);
      D[ns][0] = cvtpk(e0, e1);
      D[ns][1] = cvtpk(e2, e3);
    }
    // redistribute: target dword t of B-frag (kk) = P[k = kk*32+quad*8+2t,+1]
    // source reg: D[2kk + (quad>>1)][t&1]; source lane: adr(t>>1).
#pragma unroll
    for (int kk = 0; kk < 2; ++kk) {
      union { unsigned int u[4]; bf16x8 v; } pf;
#pragma unroll
      for (int t = 0; t < 4; ++t) {
        const int adr = (t >> 1) ? adr1 : adr0;
        const int lo = __builtin_amdgcn_ds_bpermute(adr, (int)D[2 * kk][t & 1]);
        const int hi = __builtin_amdgcn_ds_bpermute(adr, (int)D[2 * kk + 1][t & 1]);
        pf.u[t] = (unsigned int)((quad >= 2) ? hi : lo);
      }
#pragma unroll
      for (int ns2 = 0; ns2 < 4; ++ns2) {
        const bf16x8 vf = *(const bf16x8*)(Vt + (ns2 * 16 + l15) * 72 + kk * 32 + quad * 8);
        oac[ns2] = MFMA16(vf, pf.v, oac[ns2]);   // O^T[d][q]
      }
    }
  }

  z2 += __shfl_xor(z2, 16, 64);
  z2 += __shfl_xor(z2, 32, 64);
  const int s = q0 + wave * 16 + l15;
  ushort_t* crow = ctx + ((size_t)(b * 1024 + s)) * 1024 + h * 64;
#pragma unroll
  for (int ns2 = 0; ns2 < 4; ++ns2) {
    us4 pack;
#pragma unroll
    for (int r = 0; r < 4; ++r) pack[r] = f2b(oac[ns2][r] / z2);
    *(us4*)(crow + ns2 * 16 + quad * 4) = pack;
  }
}

// ---------------------------------------------------------------------------
// K3: pre = ctx @ Wo_bf^T + bo -> bf16. 64x128 tiles, grid 512 (2 blocks/CU),
// 2-phase gll double-buffer, single barrier per K-step. Waves 2x2 over
// 64x128 -> per-wave 32x64, acc[2][4].
// ---------------------------------------------------------------------------
__global__ __launch_bounds__(256, 4) void out_proj_kernel(
    const ushort_t* __restrict__ ctxp, const ushort_t* __restrict__ wo,
    const float* __restrict__ bo, ushort_t* __restrict__ pre) {
  __shared__ __align__(16) ushort_t Asl0[64 * 32];
  __shared__ __align__(16) ushort_t Asl1[64 * 32];
  __shared__ __align__(16) ushort_t Bsl0[128 * 32];
  __shared__ __align__(16) ushort_t Bsl1[128 * 32];
  const int tid = threadIdx.x;
  const int wave = tid >> 6, lane = tid & 63;
  const int l15 = lane & 15, quad = lane >> 4;
  const int wr = wave >> 1, wc = wave & 1;
  const int l = blockIdx.x;
  const int xcd = l & 7, ii = l >> 3;        // 64 blocks per xcd
  const int m0 = (xcd * 8 + (ii >> 3)) * 64;
  const int n0 = (ii & 7) * 128;

  // A: wave w covers rows w*16..+15 (one gll); B: rows w*32..+31 (two gll).
  const ushort_t* Ag = ctxp + (size_t)(m0 + wave * 16 + (lane >> 2)) * 1024 + (lane & 3) * 8;
  const ushort_t* Bg0 = wo + (size_t)(n0 + wave * 32 + (lane >> 2)) * 1024 + (lane & 3) * 8;
  const ushort_t* Bg1 = wo + (size_t)(n0 + wave * 32 + 16 + (lane >> 2)) * 1024 + (lane & 3) * 8;

  // prologue: tile0 -> buf0
  gll16(Ag, Asl0 + wave * 512);
  gll16(Bg0, Bsl0 + wave * 1024);
  gll16(Bg1, Bsl0 + wave * 1024 + 512);
  __syncthreads();

  f32x4 acc[2][4] = {};
#define OUTP_COMPUTE(ASL, BSL)                                                  \
  {                                                                             \
    bf16x8 af[2], bfr[4];                                                       \
    _Pragma("unroll") for (int s = 0; s < 2; ++s)                               \
        af[s] = *(const bf16x8*)((ASL) + (wr * 32 + s * 16 + l15) * 32 + quad * 8); \
    _Pragma("unroll") for (int s = 0; s < 4; ++s)                               \
        bfr[s] = *(const bf16x8*)((BSL) + (wc * 64 + s * 16 + l15) * 32 + quad * 8); \
    _Pragma("unroll") for (int ms = 0; ms < 2; ++ms)                            \
        _Pragma("unroll") for (int ns = 0; ns < 4; ++ns)                        \
            acc[ms][ns] = MFMA16(af[ms], bfr[ns], acc[ms][ns]);                 \
  }

  for (int k0 = 0; k0 < 1024; k0 += 64) {
    // even half: compute buf0 (tile t), stage t+1 -> buf1
    {
      gll16(Ag + k0 + 32, Asl1 + wave * 512);
      gll16(Bg0 + k0 + 32, Bsl1 + wave * 1024);
      gll16(Bg1 + k0 + 32, Bsl1 + wave * 1024 + 512);
    }
    OUTP_COMPUTE(Asl0, Bsl0)
    __syncthreads();
    // odd half: compute buf1 (tile t+1), stage t+2 -> buf0
    if (k0 + 64 < 1024) {
      gll16(Ag + k0 + 64, Asl0 + wave * 512);
      gll16(Bg0 + k0 + 64, Bsl0 + wave * 1024);
      gll16(Bg1 + k0 + 64, Bsl0 + wave * 1024 + 512);
    }
    OUTP_COMPUTE(Asl1, Bsl1)
    __syncthreads();
  }
#undef OUTP_COMPUTE

#pragma unroll
  for (int ns = 0; ns < 4; ++ns) {
    const int col = n0 + wc * 64 + ns * 16 + l15;
    const float bv_ = bo[col];
#pragma unroll
    for (int ms = 0; ms < 2; ++ms) {
      const int rowb = m0 + wr * 32 + ms * 16 + quad * 4;
#pragma unroll
      for (int r = 0; r < 4; ++r) {
        pre[(size_t)(rowb + r) * 1024 + col] = f2b(acc[ms][ns][r] + bv_);
      }
    }
  }
}

// ---------------------------------------------------------------------------
// K4: out = LayerNorm(pre_bf16 + Q)*g + b -> f32. One block per row.
// ---------------------------------------------------------------------------
__global__ __launch_bounds__(256, 4) void ln_kernel(
    const ushort_t* __restrict__ pre, const float* __restrict__ Q,
    const float* __restrict__ g, const float* __restrict__ bta,
    float* __restrict__ out) {
  const int row = blockIdx.x;
  const int tid = threadIdx.x;
  const size_t base = (size_t)row * 1024 + tid * 4;
  const ushort4 p4 = *(const ushort4*)(pre + base);
  const float4 q4 = *(const float4*)(Q + base);
  float v[4] = {b2f(p4.x) + q4.x, b2f(p4.y) + q4.y,
                b2f(p4.z) + q4.z, b2f(p4.w) + q4.w};
  float s1 = v[0] + v[1] + v[2] + v[3];
  float s2 = v[0]*v[0] + v[1]*v[1] + v[2]*v[2] + v[3]*v[3];
#pragma unroll
  for (int off = 1; off < 64; off <<= 1) {
    s1 += __shfl_xor(s1, off, 64);
    s2 += __shfl_xor(s2, off, 64);
  }
  __shared__ float r1[4], r2[4];
  const int wave = tid >> 6, lane = tid & 63;
  if (lane == 0) { r1[wave] = s1; r2[wave] = s2; }
  __syncthreads();
  const float t1 = r1[0] + r1[1] + r1[2] + r1[3];
  const float t2 = r2[0] + r2[1] + r2[2] + r2[3];
  const float mu = t1 * (1.0f / 1024.0f);
  const float var = t2 * (1.0f / 1024.0f) - mu * mu;
  const float inv = rsqrtf(var + 1e-5f);
  const int c0 = tid * 4;
#pragma unroll
  for (int j = 0; j < 4; ++j) {
    const int c = c0 + j;
    out[(size_t)row * 1024 + c] = (v[j] - mu) * inv * g[c] + bta[c];
  }
}

// ---------------------------------------------------------------------------
extern "C" void kernel_launch(void* const* d_in, const int* in_sizes, int n_in,
                              void* d_out, int out_size, void* d_ws, size_t ws_size,
                              hipStream_t stream) {
  const float* Q  = (const float*)d_in[0];
  const float* K  = (const float*)d_in[1];
  const float* V  = (const float*)d_in[2];
  const float* Wq = (const float*)d_in[3];
  const float* bq = (const float*)d_in[4];
  const float* Wk = (const float*)d_in[5];
  const float* bk = (const float*)d_in[6];
  const float* Wv = (const float*)d_in[7];
  const float* bv = (const float*)d_in[8];
  const float* Wo = (const float*)d_in[9];
  const float* bo = (const float*)d_in[10];
  const float* lg = (const float*)d_in[11];
  const float* lb = (const float*)d_in[12];

  char* ws = (char*)d_ws;                       // 24 MB used
  ushort_t* qb  = (ushort_t*)(ws);                         // [B,S,D] bf16, scaled
  ushort_t* kb  = (ushort_t*)(ws + ((size_t)8  << 20));    // [B,S,D] bf16
  ushort_t* vb  = (ushort_t*)(ws + ((size_t)16 << 20));    // [B,H,dk,S] bf16
  ushort_t* pre = (ushort_t*)(ws);              // bf16, aliases qb (dead by K3)

  ushort_t* dptr  = (ushort_t*)d_out;           // u16 view of 16MB output
  ushort_t* wo_bf = dptr;                       // [0,1M) elems
  ushort_t* wq_bf = dptr + 1048576;             // [1M,2M)
  ushort_t* wk_bf = dptr + 2097152;             // [2M,3M)
  ushort_t* wv_bf = dptr + 3145728;             // [3M,4M)
  ushort_t* ctx   = dptr + 4194304;             // [4M,8M) = bytes [8MB,16MB)
  float*    out   = (float*)d_out;

  cvt4_kernel<<<dim3(512, 4), 256, 0, stream>>>(Wo, Wq, Wk, Wv, dptr);
  qkv_proj_kernel<<<dim3(256, 1, 3), 256, 0, stream>>>(Q, K, V, wq_bf, wk_bf, wv_bf,
                                                       bq, bk, bv, qb, kb, vb);
  attn_kernel<<<dim3(1024), 256, 0, stream>>>(qb, kb, vb, ctx);
  out_proj_kernel<<<dim3(512), 256, 0, stream>>>(ctx, wo_bf, bo, pre);
  ln_kernel<<<dim3(4096), 256, 0, stream>>>(pre, Q, lg, lb, out);
}

// Round 5
// 236.901 us; speedup vs baseline: 1.4793x; 1.4793x over previous
//
#include <hip/hip_runtime.h>
#include <cstdint>
#include <cstddef>

// ---------------------------------------------------------------------------
// MultiheadAttention (double-softmax), MI355X. B=4,S=1024,D=1024,H=16.
// Inputs FP32 (dict order), output FP32. r16:240.1 r17:338.9 r18:350.5 µs.
// r19: REVERT qkv to r16 structure (r17/r18 reg-staged A spilled both times:
// VGPR 84 + 64 acc at the 170-reg cap, WRITE_SIZE 180-210MB scratch, 160+ µs;
// r16 measured 63-65 µs, VGPR 72, WRITE 25-31MB). One safe delta kept from
// r17: staging cvt uses v_cvt_pk_bf16_f32 (4 ops/8 vals vs ~24 for the f2b
// chain; same RNE) in qkv + cvt4. attn keeps r17 swapped-QK^T structure.
//   K0 cvt4: Wo,Wq,Wk,Wv fp32->bf16 into d_out[0,8MB) (dead until ln)
//   K1 qkv : q,k -> [B,S,D] bf16 (q*0.125*log2e); v -> [B,H,dk,S] bf16
//   K2 attn: two-pass double softmax, no-max softmax1 (scores << 88)
//   K3 outp: 64x128 tiles, ctx @ Wo_bf^T + bo -> pre bf16
//   K4 ln  : LayerNorm(pre + Q)*g + b -> d_out f32 [0,16MB)
// ws (24 MB): qb[0,8) kb[8,16) vb[16,24); pre bf16 aliases [0,8) (qb dead).
// d_out u16 view: wo[0,1M) wq[1M,2M) wk[2M,3M) wv[3M,4M) ctx[4M,8M).
// ---------------------------------------------------------------------------

typedef unsigned short ushort_t;
typedef __attribute__((ext_vector_type(8))) short bf16x8;     // MFMA A/B frag
typedef __attribute__((ext_vector_type(8))) unsigned short us8;
typedef __attribute__((ext_vector_type(4))) unsigned short us4;
typedef __attribute__((ext_vector_type(4))) float f32x4;      // MFMA C/D frag

#define MFMA16(a, b, c) __builtin_amdgcn_mfma_f32_16x16x32_bf16((a), (b), (c), 0, 0, 0)
#define EXP2F(x) __builtin_amdgcn_exp2f(x)
#define LOG2E 1.4426950408889634f

__device__ __forceinline__ float b2f(ushort_t u) {
  union { unsigned int i; float f; } x; x.i = ((unsigned int)u) << 16; return x.f;
}
__device__ __forceinline__ ushort_t f2b(float f) {
  union { unsigned int i; float f; } x; x.f = f;
  unsigned int r = (x.i + 0x7FFFu + ((x.i >> 16) & 1u)) >> 16;  // RNE
  return (ushort_t)r;
}
// HW packed f32->bf16 (RNE), 2 values / instruction.
__device__ __forceinline__ unsigned int cvtpk(float lo, float hi) {
  unsigned int r;
  asm("v_cvt_pk_bf16_f32 %0, %1, %2" : "=v"(r) : "v"(lo), "v"(hi));
  return r;
}
__device__ __forceinline__ us8 cvt8pk(float4 a, float4 b) {
  union { unsigned int u[4]; us8 v; } r;
  r.u[0] = cvtpk(a.x, a.y); r.u[1] = cvtpk(a.z, a.w);
  r.u[2] = cvtpk(b.x, b.y); r.u[3] = cvtpk(b.z, b.w);
  return r.v;
}

// async global->LDS, 16B per lane; lds base must be wave-uniform.
__device__ __forceinline__ void gll16(const ushort_t* g, ushort_t* l) {
  __builtin_amdgcn_global_load_lds(
      (const __attribute__((address_space(1))) void*)g,
      (__attribute__((address_space(3))) void*)l, 16, 0, 0);
}

// ---------------------------------------------------------------------------
// K0: convert 4 weight matrices (1M fp32 elems each) to bf16.
// ---------------------------------------------------------------------------
__global__ __launch_bounds__(256, 8) void cvt4_kernel(
    const float* __restrict__ w0, const float* __restrict__ w1,
    const float* __restrict__ w2, const float* __restrict__ w3,
    ushort_t* __restrict__ dst) {
  const int which = blockIdx.y;
  const float* src = (which == 0) ? w0 : (which == 1) ? w1 : (which == 2) ? w2 : w3;
  const int i = (blockIdx.x * 256 + threadIdx.x) * 8;
  const float4 a = *(const float4*)(src + i);
  const float4 b = *(const float4*)(src + i + 4);
  *(us8*)(dst + (size_t)which * 1048576 + i) = cvt8pk(a, b);
}

// ---------------------------------------------------------------------------
// K1: Q/K/V projections. 128x128 tile, BK=32, 2-phase LDS double-buffer:
// stage tile t+1 (gll B + cvt_pk/ds_write A from ping-pong regs) BEFORE the
// MFMA on tile t; single __syncthreads per K-step. Grid (256,1,3) = 3/CU.
// XCD swizzle: xcd = bid&7 owns m-tiles [xcd*4,+4) x all 8 n-tiles.
// (r16-proven structure: 63-65 µs, VGPR 72, no spill.)
// ---------------------------------------------------------------------------
__global__ __launch_bounds__(256, 3) void qkv_proj_kernel(
    const float* __restrict__ Qin, const float* __restrict__ Kin,
    const float* __restrict__ Vin,
    const ushort_t* __restrict__ wq, const ushort_t* __restrict__ wk,
    const ushort_t* __restrict__ wv,
    const float* __restrict__ bq, const float* __restrict__ bk,
    const float* __restrict__ bv,
    ushort_t* __restrict__ qb, ushort_t* __restrict__ kb,
    ushort_t* __restrict__ vb) {
  __shared__ __align__(16) ushort_t Asl0[128 * 32];
  __shared__ __align__(16) ushort_t Asl1[128 * 32];
  __shared__ __align__(16) ushort_t Bsl0[128 * 32];
  __shared__ __align__(16) ushort_t Bsl1[128 * 32];
  const float* A; const ushort_t* W; const float* bias; float scale;
  if (blockIdx.z == 0)      { A = Qin; W = wq; bias = bq; scale = 0.125f * LOG2E; }
  else if (blockIdx.z == 1) { A = Kin; W = wk; bias = bk; scale = 1.0f; }
  else                      { A = Vin; W = wv; bias = bv; scale = 1.0f; }
  const int l = blockIdx.x;
  const int xcd = l & 7, ii = l >> 3;
  const int m0 = (xcd * 4 + (ii >> 3)) * 128;
  const int n0 = (ii & 7) * 128;
  const int tid = threadIdx.x;
  const int wave = tid >> 6, lane = tid & 63;
  const int l15 = lane & 15, quad = lane >> 4;
  const int wr = wave >> 1, wc = wave & 1;

  // A staging: thread covers rows ra, ra+64; cols ca..ca+7 (fp32 -> bf16)
  const int ra = tid >> 2, ca = (tid & 3) * 8;
  const float* Ap0 = A + (size_t)(m0 + ra) * 1024 + ca;
  const float* Ap1 = A + (size_t)(m0 + ra + 64) * 1024 + ca;

  // B staging via gll: wave w covers dest rows w*32..+15 and +16..+31.
  const ushort_t* Bg0 = W + (size_t)(n0 + wave * 32 + (lane >> 2)) * 1024 + (lane & 3) * 8;
  const ushort_t* Bg1 = W + (size_t)(n0 + wave * 32 + 16 + (lane >> 2)) * 1024 + (lane & 3) * 8;

  // prologue: tile0 -> buf0; preload tile1 into Y regs
  float4 xa0 = *(const float4*)(Ap0), xa1 = *(const float4*)(Ap0 + 4);
  float4 xa2 = *(const float4*)(Ap1), xa3 = *(const float4*)(Ap1 + 4);
  gll16(Bg0, Bsl0 + wave * 1024);
  gll16(Bg1, Bsl0 + wave * 1024 + 512);
  *(us8*)(Asl0 + ra * 32 + ca) = cvt8pk(xa0, xa1);
  *(us8*)(Asl0 + (ra + 64) * 32 + ca) = cvt8pk(xa2, xa3);
  float4 ya0 = *(const float4*)(Ap0 + 32), ya1 = *(const float4*)(Ap0 + 36);
  float4 ya2 = *(const float4*)(Ap1 + 32), ya3 = *(const float4*)(Ap1 + 36);
  __syncthreads();

  f32x4 acc[4][4] = {};
#define QKV_COMPUTE(ASL, BSL)                                                   \
  {                                                                             \
    bf16x8 af[4], bfr[4];                                                       \
    _Pragma("unroll") for (int s = 0; s < 4; ++s)                               \
        af[s] = *(const bf16x8*)((ASL) + (wr * 64 + s * 16 + l15) * 32 + quad * 8); \
    _Pragma("unroll") for (int s = 0; s < 4; ++s)                               \
        bfr[s] = *(const bf16x8*)((BSL) + (wc * 64 + s * 16 + l15) * 32 + quad * 8); \
    _Pragma("unroll") for (int ms = 0; ms < 4; ++ms)                            \
        _Pragma("unroll") for (int ns = 0; ns < 4; ++ns)                        \
            acc[ms][ns] = MFMA16(af[ms], bfr[ns], acc[ms][ns]);                 \
  }

  for (int k0 = 0; k0 < 1024; k0 += 64) {
    // even half: compute tile t (buf0); stage t+1 from Y -> buf1; load X <- t+2
    {
      gll16(Bg0 + k0 + 32, Bsl1 + wave * 1024);
      gll16(Bg1 + k0 + 32, Bsl1 + wave * 1024 + 512);
      *(us8*)(Asl1 + ra * 32 + ca) = cvt8pk(ya0, ya1);
      *(us8*)(Asl1 + (ra + 64) * 32 + ca) = cvt8pk(ya2, ya3);
    }
    if (k0 + 64 < 1024) {
      xa0 = *(const float4*)(Ap0 + k0 + 64); xa1 = *(const float4*)(Ap0 + k0 + 68);
      xa2 = *(const float4*)(Ap1 + k0 + 64); xa3 = *(const float4*)(Ap1 + k0 + 68);
    }
    QKV_COMPUTE(Asl0, Bsl0)
    __syncthreads();
    // odd half: compute tile t+1 (buf1); stage t+2 from X -> buf0; load Y <- t+3
    if (k0 + 64 < 1024) {
      gll16(Bg0 + k0 + 64, Bsl0 + wave * 1024);
      gll16(Bg1 + k0 + 64, Bsl0 + wave * 1024 + 512);
      *(us8*)(Asl0 + ra * 32 + ca) = cvt8pk(xa0, xa1);
      *(us8*)(Asl0 + (ra + 64) * 32 + ca) = cvt8pk(xa2, xa3);
      if (k0 + 96 < 1024) {
        ya0 = *(const float4*)(Ap0 + k0 + 96); ya1 = *(const float4*)(Ap0 + k0 + 100);
        ya2 = *(const float4*)(Ap1 + k0 + 96); ya3 = *(const float4*)(Ap1 + k0 + 100);
      }
    }
    QKV_COMPUTE(Asl1, Bsl1)
    __syncthreads();
  }
#undef QKV_COMPUTE

  if (blockIdx.z != 2) {
    ushort_t* outp = (blockIdx.z == 0) ? qb : kb;
#pragma unroll
    for (int ns = 0; ns < 4; ++ns) {
      const int col = n0 + wc * 64 + ns * 16 + l15;
      const float bv_ = bias[col];
#pragma unroll
      for (int ms = 0; ms < 4; ++ms) {
        const int rowb = m0 + wr * 64 + ms * 16 + quad * 4;
#pragma unroll
        for (int r = 0; r < 4; ++r) {
          outp[(size_t)(rowb + r) * 1024 + col] =
              f2b((acc[ms][ns][r] + bv_) * scale);
        }
      }
    }
  } else {
    // V transposed: vb[((b*16+h)*64 + d)*1024 + s]
#pragma unroll
    for (int ns = 0; ns < 4; ++ns) {
      const int col = n0 + wc * 64 + ns * 16 + l15;
      const float bv_ = bias[col];
      const int h = col >> 6, d = col & 63;
#pragma unroll
      for (int ms = 0; ms < 4; ++ms) {
        const int i0 = m0 + wr * 64 + ms * 16 + quad * 4;
        const int b = i0 >> 10, s0 = i0 & 1023;
        us4 pack;
#pragma unroll
        for (int r = 0; r < 4; ++r) pack[r] = f2b(acc[ms][ns][r] + bv_);
        *(us4*)(vb + ((size_t)(b * 16 + h) * 64 + d) * 1024 + s0) = pack;
      }
    }
  }
}

// ---------------------------------------------------------------------------
// K2: attention, double softmax, SWAPPED QK^T: sc = mfma(K_frag, Q_frag) so
// thread (quad,l15) holds S[k = ns*16+quad*4+r][q = l15]. Softmax sums are
// scalar per thread (reduce over quads: 2 shuffles). P->PV redistribution
// in-register: cvt_pk pairs + 16 ds_bpermute + 8 cndmask (cross-quad move,
// same l15). PV: oac = mfma(V_frag, P_frag) -> O^T[d][q], d contiguous in
// regs -> 4 packed us4 ctx stores. No Ps LDS, no lgkm hard-sync.
// Grid 1024 (swizzled: xcd owns 8 bh x 16 q-tiles).
// ---------------------------------------------------------------------------
__global__ __launch_bounds__(256, 4) void attn_kernel(
    const ushort_t* __restrict__ qb, const ushort_t* __restrict__ kb,
    const ushort_t* __restrict__ vb, ushort_t* __restrict__ ctx) {
  __shared__ __align__(16) ushort_t Qs[64 * 72];
  __shared__ __align__(16) ushort_t Ks[64 * 72];
  __shared__ __align__(16) ushort_t Vt[64 * 72];

  const int tid = threadIdx.x, wave = tid >> 6, lane = tid & 63;
  const int l15 = lane & 15, quad = lane >> 4;
  // XCD-aware swizzle
  const int l = blockIdx.x;
  const int xcd = l & 7, ii = l >> 3;
  const int bh = xcd * 8 + (ii >> 4);
  const int q0 = (ii & 15) * 64;
  const int b = bh >> 4, h = bh & 15;
  const ushort_t* qg = qb + ((size_t)b << 20) + h * 64;
  const ushort_t* kg = kb + ((size_t)b << 20) + h * 64;
  const ushort_t* vg = vb + ((size_t)bh << 16);   // [dk][S]

  const int kr0 = tid >> 3, kc0 = (tid & 7) * 8;
  const int kr1 = (tid + 256) >> 3, kc1 = kc0;

  *(us8*)(Qs + kr0 * 72 + kc0) = *(const us8*)(qg + (size_t)(q0 + kr0) * 1024 + kc0);
  *(us8*)(Qs + kr1 * 72 + kc1) = *(const us8*)(qg + (size_t)(q0 + kr1) * 1024 + kc1);
  __syncthreads();
  // Q fragments (B-operand: lane l15 = q-col, quad*8 = k) — kt-invariant.
  bf16x8 aqh[2];
  aqh[0] = *(const bf16x8*)(Qs + (wave * 16 + l15) * 72 + quad * 8);
  aqh[1] = *(const bf16x8*)(Qs + (wave * 16 + l15) * 72 + 32 + quad * 8);

  // ---- pass 1: Z1 only ----
  float z1 = 0.f;
  us8 rk0 = *(const us8*)(kg + (size_t)kr0 * 1024 + kc0);
  us8 rk1 = *(const us8*)(kg + (size_t)kr1 * 1024 + kc1);
  for (int kt = 0; kt < 16; ++kt) {
    __syncthreads();
    *(us8*)(Ks + kr0 * 72 + kc0) = rk0;
    *(us8*)(Ks + kr1 * 72 + kc1) = rk1;
    __syncthreads();
    if (kt < 15) {
      rk0 = *(const us8*)(kg + (size_t)((kt + 1) * 64 + kr0) * 1024 + kc0);
      rk1 = *(const us8*)(kg + (size_t)((kt + 1) * 64 + kr1) * 1024 + kc1);
    }
    f32x4 sc[4] = {};
#pragma unroll
    for (int kk = 0; kk < 2; ++kk) {
#pragma unroll
      for (int ns = 0; ns < 4; ++ns) {
        const bf16x8 kf = *(const bf16x8*)(Ks + (ns * 16 + l15) * 72 + kk * 32 + quad * 8);
        sc[ns] = MFMA16(kf, aqh[kk], sc[ns]);   // swapped: rows=k, cols=q
      }
    }
#pragma unroll
    for (int ns = 0; ns < 4; ++ns)
#pragma unroll
      for (int r = 0; r < 4; ++r) z1 += EXP2F(sc[ns][r]);
  }
  z1 += __shfl_xor(z1, 16, 64);
  z1 += __shfl_xor(z1, 32, 64);
  const float iz1 = LOG2E / z1;    // e2 = exp2(exp2(sc) * iz1)

  // bpermute source addrs (bytes): src lane = ((quad&1)*2 + (t>>1))*16 + l15
  const int adr0 = ((((quad & 1) << 1) * 16) + l15) << 2;
  const int adr1 = adr0 + 64;

  // ---- pass 2 ----
  f32x4 oac[4] = {};
  float z2 = 0.f;
  rk0 = *(const us8*)(kg + (size_t)kr0 * 1024 + kc0);
  rk1 = *(const us8*)(kg + (size_t)kr1 * 1024 + kc1);
  us8 rv0 = *(const us8*)(vg + (size_t)kr0 * 1024 + kc0);
  us8 rv1 = *(const us8*)(vg + (size_t)kr1 * 1024 + kc1);
  for (int kt = 0; kt < 16; ++kt) {
    __syncthreads();
    *(us8*)(Ks + kr0 * 72 + kc0) = rk0;
    *(us8*)(Ks + kr1 * 72 + kc1) = rk1;
    *(us8*)(Vt + kr0 * 72 + kc0) = rv0;
    *(us8*)(Vt + kr1 * 72 + kc1) = rv1;
    __syncthreads();
    if (kt < 15) {
      rk0 = *(const us8*)(kg + (size_t)((kt + 1) * 64 + kr0) * 1024 + kc0);
      rk1 = *(const us8*)(kg + (size_t)((kt + 1) * 64 + kr1) * 1024 + kc1);
      rv0 = *(const us8*)(vg + (size_t)kr0 * 1024 + (kt + 1) * 64 + kc0);
      rv1 = *(const us8*)(vg + (size_t)kr1 * 1024 + (kt + 1) * 64 + kc1);
    }
    f32x4 sc[4] = {};
#pragma unroll
    for (int kk = 0; kk < 2; ++kk) {
#pragma unroll
      for (int ns = 0; ns < 4; ++ns) {
        const bf16x8 kf = *(const bf16x8*)(Ks + (ns * 16 + l15) * 72 + kk * 32 + quad * 8);
        sc[ns] = MFMA16(kf, aqh[kk], sc[ns]);
      }
    }
    // softmax epilogue: e2 per score; pack k-pairs (per thread: q=l15 fixed,
    // k = ns*16 + quad*4 + r).
    unsigned int D[4][2];
#pragma unroll
    for (int ns = 0; ns < 4; ++ns) {
      const float e0 = EXP2F(EXP2F(sc[ns][0]) * iz1);
      const float e1 = EXP2F(EXP2F(sc[ns][1]) * iz1);
      const float e2 = EXP2F(EXP2F(sc[ns][2]) * iz1);
      const float e3 = EXP2F(EXP2F(sc[ns][3]) * iz1);
      z2 += (e0 + e1) + (e2 + e3);
      D[ns][0] = cvtpk(e0, e1);
      D[ns][1] = cvtpk(e2, e3);
    }
    // redistribute: target dword t of B-frag (kk) = P[k = kk*32+quad*8+2t,+1]
    // source reg: D[2kk + (quad>>1)][t&1]; source lane: adr(t>>1).
#pragma unroll
    for (int kk = 0; kk < 2; ++kk) {
      union { unsigned int u[4]; bf16x8 v; } pf;
#pragma unroll
      for (int t = 0; t < 4; ++t) {
        const int adr = (t >> 1) ? adr1 : adr0;
        const int lo = __builtin_amdgcn_ds_bpermute(adr, (int)D[2 * kk][t & 1]);
        const int hi = __builtin_amdgcn_ds_bpermute(adr, (int)D[2 * kk + 1][t & 1]);
        pf.u[t] = (unsigned int)((quad >= 2) ? hi : lo);
      }
#pragma unroll
      for (int ns2 = 0; ns2 < 4; ++ns2) {
        const bf16x8 vf = *(const bf16x8*)(Vt + (ns2 * 16 + l15) * 72 + kk * 32 + quad * 8);
        oac[ns2] = MFMA16(vf, pf.v, oac[ns2]);   // O^T[d][q]
      }
    }
  }

  z2 += __shfl_xor(z2, 16, 64);
  z2 += __shfl_xor(z2, 32, 64);
  const int s = q0 + wave * 16 + l15;
  ushort_t* crow = ctx + ((size_t)(b * 1024 + s)) * 1024 + h * 64;
#pragma unroll
  for (int ns2 = 0; ns2 < 4; ++ns2) {
    us4 pack;
#pragma unroll
    for (int r = 0; r < 4; ++r) pack[r] = f2b(oac[ns2][r] / z2);
    *(us4*)(crow + ns2 * 16 + quad * 4) = pack;
  }
}

// ---------------------------------------------------------------------------
// K3: pre = ctx @ Wo_bf^T + bo -> bf16. 64x128 tiles, grid 512 (2 blocks/CU),
// 2-phase gll double-buffer, single barrier per K-step. Waves 2x2 over
// 64x128 -> per-wave 32x64, acc[2][4].
// ---------------------------------------------------------------------------
__global__ __launch_bounds__(256, 4) void out_proj_kernel(
    const ushort_t* __restrict__ ctxp, const ushort_t* __restrict__ wo,
    const float* __restrict__ bo, ushort_t* __restrict__ pre) {
  __shared__ __align__(16) ushort_t Asl0[64 * 32];
  __shared__ __align__(16) ushort_t Asl1[64 * 32];
  __shared__ __align__(16) ushort_t Bsl0[128 * 32];
  __shared__ __align__(16) ushort_t Bsl1[128 * 32];
  const int tid = threadIdx.x;
  const int wave = tid >> 6, lane = tid & 63;
  const int l15 = lane & 15, quad = lane >> 4;
  const int wr = wave >> 1, wc = wave & 1;
  const int l = blockIdx.x;
  const int xcd = l & 7, ii = l >> 3;        // 64 blocks per xcd
  const int m0 = (xcd * 8 + (ii >> 3)) * 64;
  const int n0 = (ii & 7) * 128;

  // A: wave w covers rows w*16..+15 (one gll); B: rows w*32..+31 (two gll).
  const ushort_t* Ag = ctxp + (size_t)(m0 + wave * 16 + (lane >> 2)) * 1024 + (lane & 3) * 8;
  const ushort_t* Bg0 = wo + (size_t)(n0 + wave * 32 + (lane >> 2)) * 1024 + (lane & 3) * 8;
  const ushort_t* Bg1 = wo + (size_t)(n0 + wave * 32 + 16 + (lane >> 2)) * 1024 + (lane & 3) * 8;

  // prologue: tile0 -> buf0
  gll16(Ag, Asl0 + wave * 512);
  gll16(Bg0, Bsl0 + wave * 1024);
  gll16(Bg1, Bsl0 + wave * 1024 + 512);
  __syncthreads();

  f32x4 acc[2][4] = {};
#define OUTP_COMPUTE(ASL, BSL)                                                  \
  {                                                                             \
    bf16x8 af[2], bfr[4];                                                       \
    _Pragma("unroll") for (int s = 0; s < 2; ++s)                               \
        af[s] = *(const bf16x8*)((ASL) + (wr * 32 + s * 16 + l15) * 32 + quad * 8); \
    _Pragma("unroll") for (int s = 0; s < 4; ++s)                               \
        bfr[s] = *(const bf16x8*)((BSL) + (wc * 64 + s * 16 + l15) * 32 + quad * 8); \
    _Pragma("unroll") for (int ms = 0; ms < 2; ++ms)                            \
        _Pragma("unroll") for (int ns = 0; ns < 4; ++ns)                        \
            acc[ms][ns] = MFMA16(af[ms], bfr[ns], acc[ms][ns]);                 \
  }

  for (int k0 = 0; k0 < 1024; k0 += 64) {
    // even half: compute buf0 (tile t), stage t+1 -> buf1
    {
      gll16(Ag + k0 + 32, Asl1 + wave * 512);
      gll16(Bg0 + k0 + 32, Bsl1 + wave * 1024);
      gll16(Bg1 + k0 + 32, Bsl1 + wave * 1024 + 512);
    }
    OUTP_COMPUTE(Asl0, Bsl0)
    __syncthreads();
    // odd half: compute buf1 (tile t+1), stage t+2 -> buf0
    if (k0 + 64 < 1024) {
      gll16(Ag + k0 + 64, Asl0 + wave * 512);
      gll16(Bg0 + k0 + 64, Bsl0 + wave * 1024);
      gll16(Bg1 + k0 + 64, Bsl0 + wave * 1024 + 512);
    }
    OUTP_COMPUTE(Asl1, Bsl1)
    __syncthreads();
  }
#undef OUTP_COMPUTE

#pragma unroll
  for (int ns = 0; ns < 4; ++ns) {
    const int col = n0 + wc * 64 + ns * 16 + l15;
    const float bv_ = bo[col];
#pragma unroll
    for (int ms = 0; ms < 2; ++ms) {
      const int rowb = m0 + wr * 32 + ms * 16 + quad * 4;
#pragma unroll
      for (int r = 0; r < 4; ++r) {
        pre[(size_t)(rowb + r) * 1024 + col] = f2b(acc[ms][ns][r] + bv_);
      }
    }
  }
}

// ---------------------------------------------------------------------------
// K4: out = LayerNorm(pre_bf16 + Q)*g + b -> f32. One block per row.
// ---------------------------------------------------------------------------
__global__ __launch_bounds__(256, 4) void ln_kernel(
    const ushort_t* __restrict__ pre, const float* __restrict__ Q,
    const float* __restrict__ g, const float* __restrict__ bta,
    float* __restrict__ out) {
  const int row = blockIdx.x;
  const int tid = threadIdx.x;
  const size_t base = (size_t)row * 1024 + tid * 4;
  const ushort4 p4 = *(const ushort4*)(pre + base);
  const float4 q4 = *(const float4*)(Q + base);
  float v[4] = {b2f(p4.x) + q4.x, b2f(p4.y) + q4.y,
                b2f(p4.z) + q4.z, b2f(p4.w) + q4.w};
  float s1 = v[0] + v[1] + v[2] + v[3];
  float s2 = v[0]*v[0] + v[1]*v[1] + v[2]*v[2] + v[3]*v[3];
#pragma unroll
  for (int off = 1; off < 64; off <<= 1) {
    s1 += __shfl_xor(s1, off, 64);
    s2 += __shfl_xor(s2, off, 64);
  }
  __shared__ float r1[4], r2[4];
  const int wave = tid >> 6, lane = tid & 63;
  if (lane == 0) { r1[wave] = s1; r2[wave] = s2; }
  __syncthreads();
  const float t1 = r1[0] + r1[1] + r1[2] + r1[3];
  const float t2 = r2[0] + r2[1] + r2[2] + r2[3];
  const float mu = t1 * (1.0f / 1024.0f);
  const float var = t2 * (1.0f / 1024.0f) - mu * mu;
  const float inv = rsqrtf(var + 1e-5f);
  const int c0 = tid * 4;
#pragma unroll
  for (int j = 0; j < 4; ++j) {
    const int c = c0 + j;
    out[(size_t)row * 1024 + c] = (v[j] - mu) * inv * g[c] + bta[c];
  }
}

// ---------------------------------------------------------------------------
extern "C" void kernel_launch(void* const* d_in, const int* in_sizes, int n_in,
                              void* d_out, int out_size, void* d_ws, size_t ws_size,
                              hipStream_t stream) {
  const float* Q  = (const float*)d_in[0];
  const float* K  = (const float*)d_in[1];
  const float* V  = (const float*)d_in[2];
  const float* Wq = (const float*)d_in[3];
  const float* bq = (const float*)d_in[4];
  const float* Wk = (const float*)d_in[5];
  const float* bk = (const float*)d_in[6];
  const float* Wv = (const float*)d_in[7];
  const float* bv = (const float*)d_in[8];
  const float* Wo = (const float*)d_in[9];
  const float* bo = (const float*)d_in[10];
  const float* lg = (const float*)d_in[11];
  const float* lb = (const float*)d_in[12];

  char* ws = (char*)d_ws;                       // 24 MB used
  ushort_t* qb  = (ushort_t*)(ws);                         // [B,S,D] bf16, scaled
  ushort_t* kb  = (ushort_t*)(ws + ((size_t)8  << 20));    // [B,S,D] bf16
  ushort_t* vb  = (ushort_t*)(ws + ((size_t)16 << 20));    // [B,H,dk,S] bf16
  ushort_t* pre = (ushort_t*)(ws);              // bf16, aliases qb (dead by K3)

  ushort_t* dptr  = (ushort_t*)d_out;           // u16 view of 16MB output
  ushort_t* wo_bf = dptr;                       // [0,1M) elems
  ushort_t* wq_bf = dptr + 1048576;             // [1M,2M)
  ushort_t* wk_bf = dptr + 2097152;             // [2M,3M)
  ushort_t* wv_bf = dptr + 3145728;             // [3M,4M)
  ushort_t* ctx   = dptr + 4194304;             // [4M,8M) = bytes [8MB,16MB)
  float*    out   = (float*)d_out;

  cvt4_kernel<<<dim3(512, 4), 256, 0, stream>>>(Wo, Wq, Wk, Wv, dptr);
  qkv_proj_kernel<<<dim3(256, 1, 3), 256, 0, stream>>>(Q, K, V, wq_bf, wk_bf, wv_bf,
                                                       bq, bk, bv, qb, kb, vb);
  attn_kernel<<<dim3(1024), 256, 0, stream>>>(qb, kb, vb, ctx);
  out_proj_kernel<<<dim3(512), 256, 0, stream>>>(ctx, wo_bf, bo, pre);
  ln_kernel<<<dim3(4096), 256, 0, stream>>>(pre, Q, lg, lb, out);
}

// Round 6
// 235.381 us; speedup vs baseline: 1.4889x; 1.0065x over previous
//
#include <hip/hip_runtime.h>
#include <cstdint>
#include <cstddef>

// ---------------------------------------------------------------------------
// MultiheadAttention (double-softmax), MI355X. B=4,S=1024,D=1024,H=16.
// Inputs FP32 (dict order), output FP32. r16:240.1 r19:236.9 µs (best).
// r20: barrier-semantics only, dataflow identical to r19 (r17/r18 lesson:
// changing the A dataflow spills; changing only waits is register-neutral).
// (1) qkv: __syncthreads -> s_waitcnt vmcnt(4) lgkmcnt(0); s_barrier.
//     Retires exactly the 2 glls for the next B buffer; the 4 A-prefetch
//     loads ride across the barrier (r19's sync force-drained them).
//     Boundary phases without an A-reload use vmcnt(0).
// (2) attn: single barrier per KV tile. 4 rotating 9KB buffers (Qs=Sh0 is
//     dead after Q-frag hoist): pass1 K in {Sh1,Sh2}; pass2 K {Sh0,Sh1},
//     V {Sh2,Sh3}. Per tile: compute(cur) | ds_write(next) | issue load
//     (kt+2) | lgkmcnt(0)+s_barrier (vmcnt un-drained; K/V L2-resident).
//     Barriers 64 -> 34 per block. LDS total unchanged (36,864 B).
//   K0 cvt4: Wo,Wq,Wk,Wv fp32->bf16 into d_out[0,8MB) (dead until ln)
//   K1 qkv : q,k -> [B,S,D] bf16 (q*0.125*log2e); v -> [B,H,dk,S] bf16
//   K2 attn: two-pass double softmax, no-max softmax1 (scores << 88)
//   K3 outp: 64x128 tiles, ctx @ Wo_bf^T + bo -> pre bf16
//   K4 ln  : LayerNorm(pre + Q)*g + b -> d_out f32 [0,16MB)
// ws (24 MB): qb[0,8) kb[8,16) vb[16,24); pre bf16 aliases [0,8) (qb dead).
// d_out u16 view: wo[0,1M) wq[1M,2M) wk[2M,3M) wv[3M,4M) ctx[4M,8M).
// ---------------------------------------------------------------------------

typedef unsigned short ushort_t;
typedef __attribute__((ext_vector_type(8))) short bf16x8;     // MFMA A/B frag
typedef __attribute__((ext_vector_type(8))) unsigned short us8;
typedef __attribute__((ext_vector_type(4))) unsigned short us4;
typedef __attribute__((ext_vector_type(4))) float f32x4;      // MFMA C/D frag

#define MFMA16(a, b, c) __builtin_amdgcn_mfma_f32_16x16x32_bf16((a), (b), (c), 0, 0, 0)
#define EXP2F(x) __builtin_amdgcn_exp2f(x)
#define LOG2E 1.4426950408889634f

__device__ __forceinline__ float b2f(ushort_t u) {
  union { unsigned int i; float f; } x; x.i = ((unsigned int)u) << 16; return x.f;
}
__device__ __forceinline__ ushort_t f2b(float f) {
  union { unsigned int i; float f; } x; x.f = f;
  unsigned int r = (x.i + 0x7FFFu + ((x.i >> 16) & 1u)) >> 16;  // RNE
  return (ushort_t)r;
}
// HW packed f32->bf16 (RNE), 2 values / instruction.
__device__ __forceinline__ unsigned int cvtpk(float lo, float hi) {
  unsigned int r;
  asm("v_cvt_pk_bf16_f32 %0, %1, %2" : "=v"(r) : "v"(lo), "v"(hi));
  return r;
}
__device__ __forceinline__ us8 cvt8pk(float4 a, float4 b) {
  union { unsigned int u[4]; us8 v; } r;
  r.u[0] = cvtpk(a.x, a.y); r.u[1] = cvtpk(a.z, a.w);
  r.u[2] = cvtpk(b.x, b.y); r.u[3] = cvtpk(b.z, b.w);
  return r.v;
}

// async global->LDS, 16B per lane; lds base must be wave-uniform.
__device__ __forceinline__ void gll16(const ushort_t* g, ushort_t* l) {
  __builtin_amdgcn_global_load_lds(
      (const __attribute__((address_space(1))) void*)g,
      (__attribute__((address_space(3))) void*)l, 16, 0, 0);
}

// ---------------------------------------------------------------------------
// K0: convert 4 weight matrices (1M fp32 elems each) to bf16.
// ---------------------------------------------------------------------------
__global__ __launch_bounds__(256, 8) void cvt4_kernel(
    const float* __restrict__ w0, const float* __restrict__ w1,
    const float* __restrict__ w2, const float* __restrict__ w3,
    ushort_t* __restrict__ dst) {
  const int which = blockIdx.y;
  const float* src = (which == 0) ? w0 : (which == 1) ? w1 : (which == 2) ? w2 : w3;
  const int i = (blockIdx.x * 256 + threadIdx.x) * 8;
  const float4 a = *(const float4*)(src + i);
  const float4 b = *(const float4*)(src + i + 4);
  *(us8*)(dst + (size_t)which * 1048576 + i) = cvt8pk(a, b);
}

// ---------------------------------------------------------------------------
// K1: Q/K/V projections. 128x128 tile, BK=32, 2-phase LDS double-buffer
// (r19 dataflow verbatim). Barrier = s_waitcnt vmcnt(N) lgkmcnt(0) +
// s_barrier; N=4 keeps the 4 A-prefetch loads in flight, retires the 2 glls.
// FIFO ledger/phase: [A_prev(4)] +gll(2) -> ds_write waits vmcnt(2)
// (retires A_prev) -> +A_next(4) -> barrier waits vmcnt(4) (retires glls).
// Grid (256,1,3) = 3/CU. XCD swizzle: xcd owns m-tiles [xcd*4,+4) x 8 n.
// ---------------------------------------------------------------------------
__global__ __launch_bounds__(256, 3) void qkv_proj_kernel(
    const float* __restrict__ Qin, const float* __restrict__ Kin,
    const float* __restrict__ Vin,
    const ushort_t* __restrict__ wq, const ushort_t* __restrict__ wk,
    const ushort_t* __restrict__ wv,
    const float* __restrict__ bq, const float* __restrict__ bk,
    const float* __restrict__ bv,
    ushort_t* __restrict__ qb, ushort_t* __restrict__ kb,
    ushort_t* __restrict__ vb) {
  __shared__ __align__(16) ushort_t Asl0[128 * 32];
  __shared__ __align__(16) ushort_t Asl1[128 * 32];
  __shared__ __align__(16) ushort_t Bsl0[128 * 32];
  __shared__ __align__(16) ushort_t Bsl1[128 * 32];
  const float* A; const ushort_t* W; const float* bias; float scale;
  if (blockIdx.z == 0)      { A = Qin; W = wq; bias = bq; scale = 0.125f * LOG2E; }
  else if (blockIdx.z == 1) { A = Kin; W = wk; bias = bk; scale = 1.0f; }
  else                      { A = Vin; W = wv; bias = bv; scale = 1.0f; }
  const int l = blockIdx.x;
  const int xcd = l & 7, ii = l >> 3;
  const int m0 = (xcd * 4 + (ii >> 3)) * 128;
  const int n0 = (ii & 7) * 128;
  const int tid = threadIdx.x;
  const int wave = tid >> 6, lane = tid & 63;
  const int l15 = lane & 15, quad = lane >> 4;
  const int wr = wave >> 1, wc = wave & 1;

  // A staging: thread covers rows ra, ra+64; cols ca..ca+7 (fp32 -> bf16)
  const int ra = tid >> 2, ca = (tid & 3) * 8;
  const float* Ap0 = A + (size_t)(m0 + ra) * 1024 + ca;
  const float* Ap1 = A + (size_t)(m0 + ra + 64) * 1024 + ca;

  // B staging via gll: wave w covers dest rows w*32..+15 and +16..+31.
  const ushort_t* Bg0 = W + (size_t)(n0 + wave * 32 + (lane >> 2)) * 1024 + (lane & 3) * 8;
  const ushort_t* Bg1 = W + (size_t)(n0 + wave * 32 + 16 + (lane >> 2)) * 1024 + (lane & 3) * 8;

  // prologue: tile0 -> buf0; preload tile1 into Y regs
  float4 xa0 = *(const float4*)(Ap0), xa1 = *(const float4*)(Ap0 + 4);
  float4 xa2 = *(const float4*)(Ap1), xa3 = *(const float4*)(Ap1 + 4);
  gll16(Bg0, Bsl0 + wave * 1024);
  gll16(Bg1, Bsl0 + wave * 1024 + 512);
  *(us8*)(Asl0 + ra * 32 + ca) = cvt8pk(xa0, xa1);
  *(us8*)(Asl0 + (ra + 64) * 32 + ca) = cvt8pk(xa2, xa3);
  float4 ya0 = *(const float4*)(Ap0 + 32), ya1 = *(const float4*)(Ap0 + 36);
  float4 ya2 = *(const float4*)(Ap1 + 32), ya3 = *(const float4*)(Ap1 + 36);
  asm volatile("s_waitcnt vmcnt(4) lgkmcnt(0)" ::: "memory");  // retire glls, keep Y
  __builtin_amdgcn_s_barrier();

  f32x4 acc[4][4] = {};
#define QKV_COMPUTE(ASL, BSL)                                                   \
  {                                                                             \
    bf16x8 af[4], bfr[4];                                                       \
    _Pragma("unroll") for (int s = 0; s < 4; ++s)                               \
        af[s] = *(const bf16x8*)((ASL) + (wr * 64 + s * 16 + l15) * 32 + quad * 8); \
    _Pragma("unroll") for (int s = 0; s < 4; ++s)                               \
        bfr[s] = *(const bf16x8*)((BSL) + (wc * 64 + s * 16 + l15) * 32 + quad * 8); \
    _Pragma("unroll") for (int ms = 0; ms < 4; ++ms)                            \
        _Pragma("unroll") for (int ns = 0; ns < 4; ++ns)                        \
            acc[ms][ns] = MFMA16(af[ms], bfr[ns], acc[ms][ns]);                 \
  }

  for (int k0 = 0; k0 < 1024; k0 += 64) {
    // even half: compute tile t (buf0); stage t+1 from Y -> buf1; load X <- t+2
    {
      gll16(Bg0 + k0 + 32, Bsl1 + wave * 1024);
      gll16(Bg1 + k0 + 32, Bsl1 + wave * 1024 + 512);
      *(us8*)(Asl1 + ra * 32 + ca) = cvt8pk(ya0, ya1);
      *(us8*)(Asl1 + (ra + 64) * 32 + ca) = cvt8pk(ya2, ya3);
    }
    if (k0 + 64 < 1024) {
      xa0 = *(const float4*)(Ap0 + k0 + 64); xa1 = *(const float4*)(Ap0 + k0 + 68);
      xa2 = *(const float4*)(Ap1 + k0 + 64); xa3 = *(const float4*)(Ap1 + k0 + 68);
    }
    QKV_COMPUTE(Asl0, Bsl0)
    if (k0 + 64 < 1024) asm volatile("s_waitcnt vmcnt(4) lgkmcnt(0)" ::: "memory");
    else                asm volatile("s_waitcnt vmcnt(0) lgkmcnt(0)" ::: "memory");
    __builtin_amdgcn_s_barrier();
    // odd half: compute tile t+1 (buf1); stage t+2 from X -> buf0; load Y <- t+3
    if (k0 + 64 < 1024) {
      gll16(Bg0 + k0 + 64, Bsl0 + wave * 1024);
      gll16(Bg1 + k0 + 64, Bsl0 + wave * 1024 + 512);
      *(us8*)(Asl0 + ra * 32 + ca) = cvt8pk(xa0, xa1);
      *(us8*)(Asl0 + (ra + 64) * 32 + ca) = cvt8pk(xa2, xa3);
      if (k0 + 96 < 1024) {
        ya0 = *(const float4*)(Ap0 + k0 + 96); ya1 = *(const float4*)(Ap0 + k0 + 100);
        ya2 = *(const float4*)(Ap1 + k0 + 96); ya3 = *(const float4*)(Ap1 + k0 + 100);
      }
    }
    QKV_COMPUTE(Asl1, Bsl1)
    if (k0 + 96 < 1024)      asm volatile("s_waitcnt vmcnt(4) lgkmcnt(0)" ::: "memory");
    else                     asm volatile("s_waitcnt vmcnt(0) lgkmcnt(0)" ::: "memory");
    __builtin_amdgcn_s_barrier();
  }
#undef QKV_COMPUTE

  if (blockIdx.z != 2) {
    ushort_t* outp = (blockIdx.z == 0) ? qb : kb;
#pragma unroll
    for (int ns = 0; ns < 4; ++ns) {
      const int col = n0 + wc * 64 + ns * 16 + l15;
      const float bv_ = bias[col];
#pragma unroll
      for (int ms = 0; ms < 4; ++ms) {
        const int rowb = m0 + wr * 64 + ms * 16 + quad * 4;
#pragma unroll
        for (int r = 0; r < 4; ++r) {
          outp[(size_t)(rowb + r) * 1024 + col] =
              f2b((acc[ms][ns][r] + bv_) * scale);
        }
      }
    }
  } else {
    // V transposed: vb[((b*16+h)*64 + d)*1024 + s]
#pragma unroll
    for (int ns = 0; ns < 4; ++ns) {
      const int col = n0 + wc * 64 + ns * 16 + l15;
      const float bv_ = bias[col];
      const int h = col >> 6, d = col & 63;
#pragma unroll
      for (int ms = 0; ms < 4; ++ms) {
        const int i0 = m0 + wr * 64 + ms * 16 + quad * 4;
        const int b = i0 >> 10, s0 = i0 & 1023;
        us4 pack;
#pragma unroll
        for (int r = 0; r < 4; ++r) pack[r] = f2b(acc[ms][ns][r] + bv_);
        *(us4*)(vb + ((size_t)(b * 16 + h) * 64 + d) * 1024 + s0) = pack;
      }
    }
  }
}

// ---------------------------------------------------------------------------
// K2: attention, double softmax, SWAPPED QK^T (r17 math). Single barrier per
// KV tile: 4 rotating 9KB buffers. Pass1 K in {Sh1,Sh2}; pass2 K {Sh0,Sh1},
// V {Sh2,Sh3} (Sh0=Qs dead after Q-frag hoist). Per tile: QK^T(cur) ->
// ds_write(next from regs) + issue load(kt+2) -> softmax -> PV(cur) ->
// lgkmcnt(0)+s_barrier (vmcnt rides; K/V are L2-resident).
// Grid 1024 (swizzled: xcd owns 8 bh x 16 q-tiles).
// ---------------------------------------------------------------------------
__global__ __launch_bounds__(256, 4) void attn_kernel(
    const ushort_t* __restrict__ qb, const ushort_t* __restrict__ kb,
    const ushort_t* __restrict__ vb, ushort_t* __restrict__ ctx) {
  __shared__ __align__(16) ushort_t Sh0[64 * 72];
  __shared__ __align__(16) ushort_t Sh1[64 * 72];
  __shared__ __align__(16) ushort_t Sh2[64 * 72];
  __shared__ __align__(16) ushort_t Sh3[64 * 72];

  const int tid = threadIdx.x, wave = tid >> 6, lane = tid & 63;
  const int l15 = lane & 15, quad = lane >> 4;
  // XCD-aware swizzle
  const int l = blockIdx.x;
  const int xcd = l & 7, ii = l >> 3;
  const int bh = xcd * 8 + (ii >> 4);
  const int q0 = (ii & 15) * 64;
  const int b = bh >> 4, h = bh & 15;
  const ushort_t* qg = qb + ((size_t)b << 20) + h * 64;
  const ushort_t* kg = kb + ((size_t)b << 20) + h * 64;
  const ushort_t* vg = vb + ((size_t)bh << 16);   // [dk][S]

  const int kr0 = tid >> 3, kc0 = (tid & 7) * 8;
  const int kr1 = (tid + 256) >> 3, kc1 = kc0;
  const int o0 = kr0 * 72 + kc0, o1 = kr1 * 72 + kc1;

  // prologue: Q -> Sh0; K tile0 -> Sh1; issue K tile1.
  *(us8*)(Sh0 + o0) = *(const us8*)(qg + (size_t)(q0 + kr0) * 1024 + kc0);
  *(us8*)(Sh0 + o1) = *(const us8*)(qg + (size_t)(q0 + kr1) * 1024 + kc1);
  us8 rk0 = *(const us8*)(kg + (size_t)kr0 * 1024 + kc0);
  us8 rk1 = *(const us8*)(kg + (size_t)kr1 * 1024 + kc1);
  *(us8*)(Sh1 + o0) = rk0;
  *(us8*)(Sh1 + o1) = rk1;
  rk0 = *(const us8*)(kg + (size_t)(64 + kr0) * 1024 + kc0);
  rk1 = *(const us8*)(kg + (size_t)(64 + kr1) * 1024 + kc1);
  __syncthreads();
  // Q fragments (B-operand: lane l15 = q-col, quad*8 = k) — kt-invariant.
  bf16x8 aqh[2];
  aqh[0] = *(const bf16x8*)(Sh0 + (wave * 16 + l15) * 72 + quad * 8);
  aqh[1] = *(const bf16x8*)(Sh0 + (wave * 16 + l15) * 72 + 32 + quad * 8);

  // ---- pass 1: Z1 only; K tiles rotate in {Sh1, Sh2} ----
  float z1 = 0.f;
  for (int kt = 0; kt < 16; ++kt) {
    const ushort_t* kcur = (kt & 1) ? Sh2 : Sh1;
    f32x4 sc[4] = {};
#pragma unroll
    for (int kk = 0; kk < 2; ++kk) {
#pragma unroll
      for (int ns = 0; ns < 4; ++ns) {
        const bf16x8 kf = *(const bf16x8*)(kcur + (ns * 16 + l15) * 72 + kk * 32 + quad * 8);
        sc[ns] = MFMA16(kf, aqh[kk], sc[ns]);   // swapped: rows=k, cols=q
      }
    }
    if (kt < 15) {       // stage K_{kt+1} into the other buffer
      ushort_t* knxt = (kt & 1) ? Sh1 : Sh2;
      *(us8*)(knxt + o0) = rk0;
      *(us8*)(knxt + o1) = rk1;
      if (kt < 14) {
        rk0 = *(const us8*)(kg + (size_t)((kt + 2) * 64 + kr0) * 1024 + kc0);
        rk1 = *(const us8*)(kg + (size_t)((kt + 2) * 64 + kr1) * 1024 + kc1);
      }
    }
#pragma unroll
    for (int ns = 0; ns < 4; ++ns)
#pragma unroll
      for (int r = 0; r < 4; ++r) z1 += EXP2F(sc[ns][r]);
    asm volatile("s_waitcnt lgkmcnt(0)" ::: "memory");
    __builtin_amdgcn_s_barrier();
  }
  z1 += __shfl_xor(z1, 16, 64);
  z1 += __shfl_xor(z1, 32, 64);
  const float iz1 = LOG2E / z1;    // e2 = exp2(exp2(sc) * iz1)

  // bpermute source addrs (bytes): src lane = ((quad&1)*2 + (t>>1))*16 + l15
  const int adr0 = ((((quad & 1) << 1) * 16) + l15) << 2;
  const int adr1 = adr0 + 64;

  // ---- pass 2: K rotates {Sh0, Sh1}, V rotates {Sh2, Sh3} ----
  f32x4 oac[4] = {};
  float z2 = 0.f;
  rk0 = *(const us8*)(kg + (size_t)kr0 * 1024 + kc0);
  rk1 = *(const us8*)(kg + (size_t)kr1 * 1024 + kc1);
  us8 rv0 = *(const us8*)(vg + (size_t)kr0 * 1024 + kc0);
  us8 rv1 = *(const us8*)(vg + (size_t)kr1 * 1024 + kc1);
  *(us8*)(Sh0 + o0) = rk0;          // K0 (Sh0 reads all done in pass1)
  *(us8*)(Sh0 + o1) = rk1;
  *(us8*)(Sh2 + o0) = rv0;          // V0 (Sh2 reads barriered at pass1 end)
  *(us8*)(Sh2 + o1) = rv1;
  rk0 = *(const us8*)(kg + (size_t)(64 + kr0) * 1024 + kc0);
  rk1 = *(const us8*)(kg + (size_t)(64 + kr1) * 1024 + kc1);
  rv0 = *(const us8*)(vg + (size_t)kr0 * 1024 + 64 + kc0);
  rv1 = *(const us8*)(vg + (size_t)kr1 * 1024 + 64 + kc1);
  asm volatile("s_waitcnt lgkmcnt(0)" ::: "memory");
  __builtin_amdgcn_s_barrier();

  for (int kt = 0; kt < 16; ++kt) {
    const ushort_t* kcur = (kt & 1) ? Sh1 : Sh0;
    const ushort_t* vcur = (kt & 1) ? Sh3 : Sh2;
    f32x4 sc[4] = {};
#pragma unroll
    for (int kk = 0; kk < 2; ++kk) {
#pragma unroll
      for (int ns = 0; ns < 4; ++ns) {
        const bf16x8 kf = *(const bf16x8*)(kcur + (ns * 16 + l15) * 72 + kk * 32 + quad * 8);
        sc[ns] = MFMA16(kf, aqh[kk], sc[ns]);
      }
    }
    if (kt < 15) {       // stage K/V_{kt+1}; hides under softmax VALU + PV
      ushort_t* knxt = (kt & 1) ? Sh0 : Sh1;
      ushort_t* vnxt = (kt & 1) ? Sh2 : Sh3;
      *(us8*)(knxt + o0) = rk0;
      *(us8*)(knxt + o1) = rk1;
      *(us8*)(vnxt + o0) = rv0;
      *(us8*)(vnxt + o1) = rv1;
      if (kt < 14) {
        rk0 = *(const us8*)(kg + (size_t)((kt + 2) * 64 + kr0) * 1024 + kc0);
        rk1 = *(const us8*)(kg + (size_t)((kt + 2) * 64 + kr1) * 1024 + kc1);
        rv0 = *(const us8*)(vg + (size_t)kr0 * 1024 + (kt + 2) * 64 + kc0);
        rv1 = *(const us8*)(vg + (size_t)kr1 * 1024 + (kt + 2) * 64 + kc1);
      }
    }
    // softmax epilogue: e2 per score; pack k-pairs (q=l15, k=ns*16+quad*4+r).
    unsigned int D[4][2];
#pragma unroll
    for (int ns = 0; ns < 4; ++ns) {
      const float e0 = EXP2F(EXP2F(sc[ns][0]) * iz1);
      const float e1 = EXP2F(EXP2F(sc[ns][1]) * iz1);
      const float e2 = EXP2F(EXP2F(sc[ns][2]) * iz1);
      const float e3 = EXP2F(EXP2F(sc[ns][3]) * iz1);
      z2 += (e0 + e1) + (e2 + e3);
      D[ns][0] = cvtpk(e0, e1);
      D[ns][1] = cvtpk(e2, e3);
    }
    // redistribute: target dword t of B-frag (kk) = P[k = kk*32+quad*8+2t,+1]
#pragma unroll
    for (int kk = 0; kk < 2; ++kk) {
      union { unsigned int u[4]; bf16x8 v; } pf;
#pragma unroll
      for (int t = 0; t < 4; ++t) {
        const int adr = (t >> 1) ? adr1 : adr0;
        const int lo = __builtin_amdgcn_ds_bpermute(adr, (int)D[2 * kk][t & 1]);
        const int hi = __builtin_amdgcn_ds_bpermute(adr, (int)D[2 * kk + 1][t & 1]);
        pf.u[t] = (unsigned int)((quad >= 2) ? hi : lo);
      }
#pragma unroll
      for (int ns2 = 0; ns2 < 4; ++ns2) {
        const bf16x8 vf = *(const bf16x8*)(vcur + (ns2 * 16 + l15) * 72 + kk * 32 + quad * 8);
        oac[ns2] = MFMA16(vf, pf.v, oac[ns2]);   // O^T[d][q]
      }
    }
    asm volatile("s_waitcnt lgkmcnt(0)" ::: "memory");
    __builtin_amdgcn_s_barrier();
  }

  z2 += __shfl_xor(z2, 16, 64);
  z2 += __shfl_xor(z2, 32, 64);
  const int s = q0 + wave * 16 + l15;
  ushort_t* crow = ctx + ((size_t)(b * 1024 + s)) * 1024 + h * 64;
#pragma unroll
  for (int ns2 = 0; ns2 < 4; ++ns2) {
    us4 pack;
#pragma unroll
    for (int r = 0; r < 4; ++r) pack[r] = f2b(oac[ns2][r] / z2);
    *(us4*)(crow + ns2 * 16 + quad * 4) = pack;
  }
}

// ---------------------------------------------------------------------------
// K3: pre = ctx @ Wo_bf^T + bo -> bf16. 64x128 tiles, grid 512 (2 blocks/CU),
// 2-phase gll double-buffer, single barrier per K-step. Waves 2x2 over
// 64x128 -> per-wave 32x64, acc[2][4].
// ---------------------------------------------------------------------------
__global__ __launch_bounds__(256, 4) void out_proj_kernel(
    const ushort_t* __restrict__ ctxp, const ushort_t* __restrict__ wo,
    const float* __restrict__ bo, ushort_t* __restrict__ pre) {
  __shared__ __align__(16) ushort_t Asl0[64 * 32];
  __shared__ __align__(16) ushort_t Asl1[64 * 32];
  __shared__ __align__(16) ushort_t Bsl0[128 * 32];
  __shared__ __align__(16) ushort_t Bsl1[128 * 32];
  const int tid = threadIdx.x;
  const int wave = tid >> 6, lane = tid & 63;
  const int l15 = lane & 15, quad = lane >> 4;
  const int wr = wave >> 1, wc = wave & 1;
  const int l = blockIdx.x;
  const int xcd = l & 7, ii = l >> 3;        // 64 blocks per xcd
  const int m0 = (xcd * 8 + (ii >> 3)) * 64;
  const int n0 = (ii & 7) * 128;

  // A: wave w covers rows w*16..+15 (one gll); B: rows w*32..+31 (two gll).
  const ushort_t* Ag = ctxp + (size_t)(m0 + wave * 16 + (lane >> 2)) * 1024 + (lane & 3) * 8;
  const ushort_t* Bg0 = wo + (size_t)(n0 + wave * 32 + (lane >> 2)) * 1024 + (lane & 3) * 8;
  const ushort_t* Bg1 = wo + (size_t)(n0 + wave * 32 + 16 + (lane >> 2)) * 1024 + (lane & 3) * 8;

  // prologue: tile0 -> buf0
  gll16(Ag, Asl0 + wave * 512);
  gll16(Bg0, Bsl0 + wave * 1024);
  gll16(Bg1, Bsl0 + wave * 1024 + 512);
  __syncthreads();

  f32x4 acc[2][4] = {};
#define OUTP_COMPUTE(ASL, BSL)                                                  \
  {                                                                             \
    bf16x8 af[2], bfr[4];                                                       \
    _Pragma("unroll") for (int s = 0; s < 2; ++s)                               \
        af[s] = *(const bf16x8*)((ASL) + (wr * 32 + s * 16 + l15) * 32 + quad * 8); \
    _Pragma("unroll") for (int s = 0; s < 4; ++s)                               \
        bfr[s] = *(const bf16x8*)((BSL) + (wc * 64 + s * 16 + l15) * 32 + quad * 8); \
    _Pragma("unroll") for (int ms = 0; ms < 2; ++ms)                            \
        _Pragma("unroll") for (int ns = 0; ns < 4; ++ns)                        \
            acc[ms][ns] = MFMA16(af[ms], bfr[ns], acc[ms][ns]);                 \
  }

  for (int k0 = 0; k0 < 1024; k0 += 64) {
    // even half: compute buf0 (tile t), stage t+1 -> buf1
    {
      gll16(Ag + k0 + 32, Asl1 + wave * 512);
      gll16(Bg0 + k0 + 32, Bsl1 + wave * 1024);
      gll16(Bg1 + k0 + 32, Bsl1 + wave * 1024 + 512);
    }
    OUTP_COMPUTE(Asl0, Bsl0)
    __syncthreads();
    // odd half: compute buf1 (tile t+1), stage t+2 -> buf0
    if (k0 + 64 < 1024) {
      gll16(Ag + k0 + 64, Asl0 + wave * 512);
      gll16(Bg0 + k0 + 64, Bsl0 + wave * 1024);
      gll16(Bg1 + k0 + 64, Bsl0 + wave * 1024 + 512);
    }
    OUTP_COMPUTE(Asl1, Bsl1)
    __syncthreads();
  }
#undef OUTP_COMPUTE

#pragma unroll
  for (int ns = 0; ns < 4; ++ns) {
    const int col = n0 + wc * 64 + ns * 16 + l15;
    const float bv_ = bo[col];
#pragma unroll
    for (int ms = 0; ms < 2; ++ms) {
      const int rowb = m0 + wr * 32 + ms * 16 + quad * 4;
#pragma unroll
      for (int r = 0; r < 4; ++r) {
        pre[(size_t)(rowb + r) * 1024 + col] = f2b(acc[ms][ns][r] + bv_);
      }
    }
  }
}

// ---------------------------------------------------------------------------
// K4: out = LayerNorm(pre_bf16 + Q)*g + b -> f32. One block per row.
// ---------------------------------------------------------------------------
__global__ __launch_bounds__(256, 4) void ln_kernel(
    const ushort_t* __restrict__ pre, const float* __restrict__ Q,
    const float* __restrict__ g, const float* __restrict__ bta,
    float* __restrict__ out) {
  const int row = blockIdx.x;
  const int tid = threadIdx.x;
  const size_t base = (size_t)row * 1024 + tid * 4;
  const ushort4 p4 = *(const ushort4*)(pre + base);
  const float4 q4 = *(const float4*)(Q + base);
  float v[4] = {b2f(p4.x) + q4.x, b2f(p4.y) + q4.y,
                b2f(p4.z) + q4.z, b2f(p4.w) + q4.w};
  float s1 = v[0] + v[1] + v[2] + v[3];
  float s2 = v[0]*v[0] + v[1]*v[1] + v[2]*v[2] + v[3]*v[3];
#pragma unroll
  for (int off = 1; off < 64; off <<= 1) {
    s1 += __shfl_xor(s1, off, 64);
    s2 += __shfl_xor(s2, off, 64);
  }
  __shared__ float r1[4], r2[4];
  const int wave = tid >> 6, lane = tid & 63;
  if (lane == 0) { r1[wave] = s1; r2[wave] = s2; }
  __syncthreads();
  const float t1 = r1[0] + r1[1] + r1[2] + r1[3];
  const float t2 = r2[0] + r2[1] + r2[2] + r2[3];
  const float mu = t1 * (1.0f / 1024.0f);
  const float var = t2 * (1.0f / 1024.0f) - mu * mu;
  const float inv = rsqrtf(var + 1e-5f);
  const int c0 = tid * 4;
#pragma unroll
  for (int j = 0; j < 4; ++j) {
    const int c = c0 + j;
    out[(size_t)row * 1024 + c] = (v[j] - mu) * inv * g[c] + bta[c];
  }
}

// ---------------------------------------------------------------------------
extern "C" void kernel_launch(void* const* d_in, const int* in_sizes, int n_in,
                              void* d_out, int out_size, void* d_ws, size_t ws_size,
                              hipStream_t stream) {
  const float* Q  = (const float*)d_in[0];
  const float* K  = (const float*)d_in[1];
  const float* V  = (const float*)d_in[2];
  const float* Wq = (const float*)d_in[3];
  const float* bq = (const float*)d_in[4];
  const float* Wk = (const float*)d_in[5];
  const float* bk = (const float*)d_in[6];
  const float* Wv = (const float*)d_in[7];
  const float* bv = (const float*)d_in[8];
  const float* Wo = (const float*)d_in[9];
  const float* bo = (const float*)d_in[10];
  const float* lg = (const float*)d_in[11];
  const float* lb = (const float*)d_in[12];

  char* ws = (char*)d_ws;                       // 24 MB used
  ushort_t* qb  = (ushort_t*)(ws);                         // [B,S,D] bf16, scaled
  ushort_t* kb  = (ushort_t*)(ws + ((size_t)8  << 20));    // [B,S,D] bf16
  ushort_t* vb  = (ushort_t*)(ws + ((size_t)16 << 20));    // [B,H,dk,S] bf16
  ushort_t* pre = (ushort_t*)(ws);              // bf16, aliases qb (dead by K3)

  ushort_t* dptr  = (ushort_t*)d_out;           // u16 view of 16MB output
  ushort_t* wo_bf = dptr;                       // [0,1M) elems
  ushort_t* wq_bf = dptr + 1048576;             // [1M,2M)
  ushort_t* wk_bf = dptr + 2097152;             // [2M,3M)
  ushort_t* wv_bf = dptr + 3145728;             // [3M,4M)
  ushort_t* ctx   = dptr + 4194304;             // [4M,8M) = bytes [8MB,16MB)
  float*    out   = (float*)d_out;

  cvt4_kernel<<<dim3(512, 4), 256, 0, stream>>>(Wo, Wq, Wk, Wv, dptr);
  qkv_proj_kernel<<<dim3(256, 1, 3), 256, 0, stream>>>(Q, K, V, wq_bf, wk_bf, wv_bf,
                                                       bq, bk, bv, qb, kb, vb);
  attn_kernel<<<dim3(1024), 256, 0, stream>>>(qb, kb, vb, ctx);
  out_proj_kernel<<<dim3(512), 256, 0, stream>>>(ctx, wo_bf, bo, pre);
  ln_kernel<<<dim3(4096), 256, 0, stream>>>(pre, Q, lg, lb, out);
}